// Round 6
// baseline (272.078 us; speedup 1.0000x reference)
//
#include <hip/hip_runtime.h>

#define GS 128
#define GS3 (GS*GS*GS)
#define NPTS 150000
#define NBATCH 2
#define BN_TOT (NBATCH*NPTS)       // 300000
#define CONV_BLOCKS 2344           // 128 rows/block
#define BN_PAD (CONV_BLOCKS*128)   // 300032
#define ZROW   BN_PAD              // zero feature row index
#define EPS 1e-5f
#define NBKT 8192                  // 2 batches * 16^3 coarse buckets
#define NKS 28                     // 27 offsets + 1 zero slab (uniform pairing)
#define NPAIR 14

// ws layout (~97 MB)
#define OFF_GRID   0ull
#define SZ_GRID    ((size_t)NBATCH*GS3*4)            // 16,777,216
#define OFF_WFRAG  (OFF_GRID + SZ_GRID)
#define SZ_WFRAG   ((size_t)NKS*4096*2)              // 229,376 (slab 27 = zeros)
#define OFF_STATS  (OFF_WFRAG + SZ_WFRAG)            // 512
#define OFF_CNT    (OFF_STATS + 512)                 // 32,768
#define OFF_CUR    (OFF_CNT + NBKT*4)                // 32,768
#define OFF_SIDX   (OFF_CUR + NBKT*4)                // 1,200,000
#define OFF_CSORT  (OFF_SIDX + 1200128)              // BN_PAD*16
#define OFF_FB16S  (OFF_CSORT + (size_t)BN_PAD*16)   // (BN_PAD+1)*128
#define OFF_IDS    (OFF_FB16S + (size_t)(BN_PAD+1)*128)  // 28*BN_PAD*4 = 33.6MB

typedef __attribute__((ext_vector_type(8))) short bf16x8;
typedef __attribute__((ext_vector_type(4))) float f32x4;
typedef unsigned int u32;
typedef const __attribute__((address_space(1))) u32* gas_u32p;
typedef __attribute__((address_space(3))) u32* las_u32p;

__device__ __forceinline__ short f2bf(float f) {
    union { float f; unsigned u; } v; v.f = f;
    unsigned rr = v.u + 0x7fffu + ((v.u >> 16) & 1u);   // RNE
    return (short)(rr >> 16);
}

// ---------- kernel 1: grid scatter (max orig pid) + bucket histogram ----------
__global__ __launch_bounds__(256) void k_count(const int* __restrict__ coords,
                                               int* __restrict__ grid,
                                               u32* __restrict__ cnt) {
    int p = blockIdx.x*256 + threadIdx.x;
    if (p >= BN_TOT) return;
    int x = coords[p*3+0], y = coords[p*3+1], z = coords[p*3+2];
    int b = (p >= NPTS);
    atomicMax(&grid[(b<<21) | (x<<14) | (y<<7) | z], p);
    atomicAdd(&cnt[(b<<12) | ((x>>3)<<8) | ((y>>3)<<4) | (z>>3)], 1u);
}

// ---------- kernel 2: exclusive scan of 8192 bucket counts ----------
__global__ __launch_bounds__(1024) void k_scan(const u32* __restrict__ cnt,
                                               u32* __restrict__ cur) {
    __shared__ u32 ps[1024];
    int t = threadIdx.x;
    u32 l[8]; u32 s = 0;
    #pragma unroll
    for (int i = 0; i < 8; ++i) { l[i] = cnt[t*8+i]; s += l[i]; }
    ps[t] = s; __syncthreads();
    for (int off = 1; off < 1024; off <<= 1) {
        u32 v = (t >= off) ? ps[t-off] : 0u; __syncthreads();
        ps[t] += v; __syncthreads();
    }
    u32 run = (t == 0) ? 0u : ps[t-1];
    #pragma unroll
    for (int i = 0; i < 8; ++i) { cur[t*8+i] = run; run += l[i]; }
}

// ---------- kernel 3: place points in bucket order + bf16 features ----------
__global__ __launch_bounds__(256) void k_place(const float* __restrict__ feats,
                                               const int* __restrict__ coords,
                                               u32* __restrict__ cur,
                                               int* __restrict__ sortidx,
                                               int4* __restrict__ csorted,
                                               ushort* __restrict__ fb16s) {
    int p = blockIdx.x*256 + threadIdx.x;
    if (p >= BN_PAD) return;
    if (p >= BN_TOT) { csorted[p] = make_int4(-9,-9,-9,0); return; }
    int x = coords[p*3+0], y = coords[p*3+1], z = coords[p*3+2];
    int b = (p >= NPTS);
    int bkt = (b<<12) | ((x>>3)<<8) | ((y>>3)<<4) | (z>>3);
    int pos = (int)atomicAdd(&cur[bkt], 1u);
    sortidx[p] = pos;
    csorted[pos] = make_int4(x, y, z, p);
    const float4* s = (const float4*)(feats + (size_t)p*64);
    ushort* d = fb16s + (size_t)pos*64;
    #pragma unroll
    for (int i = 0; i < 8; ++i) {
        float4 a = s[2*i], c = s[2*i+1];
        ushort4 u0 = { (ushort)f2bf(a.x),(ushort)f2bf(a.y),(ushort)f2bf(a.z),(ushort)f2bf(a.w) };
        ushort4 u1 = { (ushort)f2bf(c.x),(ushort)f2bf(c.y),(ushort)f2bf(c.z),(ushort)f2bf(c.w) };
        ((ushort4*)d)[2*i] = u0; ((ushort4*)d)[2*i+1] = u1;
    }
}

// ---------- kernel 4: rulebook — sorted-id refs per sorted row, 28 slabs ----------
__global__ __launch_bounds__(256) void k_ids(const int4* __restrict__ csorted,
                                             const int* __restrict__ grid,
                                             const int* __restrict__ sortidx,
                                             int* __restrict__ ids) {
    int s = blockIdx.x*256 + threadIdx.x;
    if (s >= BN_PAD) return;
    int4 c = csorted[s];
    const bool pad = (s >= BN_TOT);
    const int gb = (c.w >= NPTS) ? GS3 : 0;
    #pragma unroll
    for (int k = 0; k < 27; ++k) {
        int dx = k/9 - 1, dy = (k/3)%3 - 1, dz = k%3 - 1;   // compile-time
        int nx = c.x+dx, ny = c.y+dy, nz = c.z+dz;
        int sid = ZROW;
        if (!pad && (((unsigned)nx < 128u) & ((unsigned)ny < 128u) &
                     ((unsigned)nz < 128u))) {
            int pid = grid[gb + (nx<<14) + (ny<<7) + nz];
            if (pid >= 0) sid = sortidx[pid];
        }
        ids[(size_t)k*BN_PAD + s] = sid;
    }
    ids[(size_t)27*BN_PAD + s] = ZROW;        // dummy slab for uniform pairing
}

// ---------- kernel 5: weight -> bf16 MFMA B-fragments (slab 27 = zeros) ----------
__global__ __launch_bounds__(256) void k_prefrag(const float* __restrict__ w,
                                                 short* __restrict__ wfrag) {
    int t = blockIdx.x * 256 + threadIdx.x;
    if (t >= NKS*4096) return;
    int i    = t & 7;
    int lane = (t >> 3) & 63;
    int tt   = (t >> 9) & 3;
    int c    = (t >> 11) & 1;
    int k    = t >> 12;
    if (k >= 27) { wfrag[t] = 0; return; }
    int kk = c*32 + (lane >> 4)*8 + i;
    int co = tt*16 + (lane & 15);
    wfrag[t] = f2bf(w[(k*64 + kk)*64 + co]);
}

// ---------- kernel 6: pipelined gathered MFMA conv, 14 k-pair phases ----------
// 4 waves/block, wave = 32 sorted rows x 64 cout. Per phase: vmcnt(8) + ONE
// barrier, 16 ds_read B, 4 global_load_lds stage(pair j+1), 32 MFMA, 8 A-loads
// for pair j+2. Invariant entering phase j: [A(j)x8, S(j)x4, A(j+1)x8].
__global__ __launch_bounds__(256, 3) void k_conv(
    const ushort* __restrict__ fb16s,
    const int4* __restrict__ csorted,
    const int* __restrict__ ids_g,
    const ushort* __restrict__ wfrag,
    float* __restrict__ out,
    float* __restrict__ gstats)
{
    __shared__ __align__(16) ushort ldsB[2][8192];   // 2 x 16KB pair buffers
    __shared__ int ids_lds[NKS*128];                 // 14.3KB block rulebook
    __shared__ float bsum[64], bsq[64];

    const int tid  = threadIdx.x;
    const int lane = tid & 63;
    const int wv   = tid >> 6;
    const int r    = lane & 15;
    const int seg  = lane >> 4;
    const int p0b  = blockIdx.x * 128;
    const int wrow = wv*32 + r;

    auto stage = [&](int jp, int bsel) {             // 16KB pair slab, 4 instr/wave
        #pragma unroll
        for (int c = 0; c < 4; ++c) {
            int chunk = c*4 + wv;
            const u32* g = (const u32*)(wfrag + (size_t)jp*8192 + chunk*512) + lane*4;
            u32* l = (u32*)(&ldsB[bsel][chunk*512]);
            __builtin_amdgcn_global_load_lds((gas_u32p)g, (las_u32p)l, 16, 0, 0);
        }
    };

#define LDA8(AC, i00, i01, i10, i11) {                                   \
        const ushort* q0_ = fb16s + (size_t)(i00)*64 + seg*8;            \
        const ushort* q1_ = fb16s + (size_t)(i01)*64 + seg*8;            \
        const ushort* q2_ = fb16s + (size_t)(i10)*64 + seg*8;            \
        const ushort* q3_ = fb16s + (size_t)(i11)*64 + seg*8;            \
        AC[0]=*(const bf16x8*)(q0_); AC[1]=*(const bf16x8*)(q0_+32);     \
        AC[2]=*(const bf16x8*)(q1_); AC[3]=*(const bf16x8*)(q1_+32);     \
        AC[4]=*(const bf16x8*)(q2_); AC[5]=*(const bf16x8*)(q2_+32);     \
        AC[6]=*(const bf16x8*)(q3_); AC[7]=*(const bf16x8*)(q3_+32); }

    f32x4 t0q0={0,0,0,0}, t0q1={0,0,0,0}, t0q2={0,0,0,0}, t0q3={0,0,0,0};
    f32x4 t1q0={0,0,0,0}, t1q1={0,0,0,0}, t1q2={0,0,0,0}, t1q3={0,0,0,0};
    bf16x8 aE[8], aO[8];

    // ---- prologue ----
    #pragma unroll
    for (int c = 0; c < NKS/2; ++c) {                // 14*256 = 28*128 ids
        int idx = c*256 + tid;
        ids_lds[idx] = ids_g[(size_t)(idx>>7)*BN_PAD + p0b + (idx&127)];
    }
    int e00 = ids_g[(size_t)0*BN_PAD + p0b + wrow], e01 = ids_g[(size_t)0*BN_PAD + p0b + wrow + 16];
    int e10 = ids_g[(size_t)1*BN_PAD + p0b + wrow], e11 = ids_g[(size_t)1*BN_PAD + p0b + wrow + 16];
    int o00 = ids_g[(size_t)2*BN_PAD + p0b + wrow], o01 = ids_g[(size_t)2*BN_PAD + p0b + wrow + 16];
    int o10 = ids_g[(size_t)3*BN_PAD + p0b + wrow], o11 = ids_g[(size_t)3*BN_PAD + p0b + wrow + 16];
    __syncthreads();                                 // ids_lds ready; drains all vmem
    __builtin_amdgcn_sched_barrier(0);
    LDA8(aE, e00, e01, e10, e11);                    // A(pair0) x8
    __builtin_amdgcn_sched_barrier(0);
    stage(0, 0);                                     // S(pair0) x4
    __builtin_amdgcn_sched_barrier(0);
    LDA8(aO, o00, o01, o10, o11);                    // A(pair1) x8
    __builtin_amdgcn_sched_barrier(0);
    // outstanding: [A(0)x8, S(0)x4, A(1)x8] = 20

    auto phaseP = [&](int j, bf16x8 (&AC)[8]) {
        asm volatile("s_waitcnt vmcnt(8)" ::: "memory");  // drain A(j)+S(j); keep A(j+1)
        __builtin_amdgcn_s_barrier();
        __builtin_amdgcn_sched_barrier(0);
        const int bsel = j & 1;
        const ushort* bb = ldsB[bsel];
        // B frags, even k of pair
        bf16x8 b0 = *(const bf16x8*)(bb + 0*512 + lane*8);
        bf16x8 b1 = *(const bf16x8*)(bb + 1*512 + lane*8);
        bf16x8 b2 = *(const bf16x8*)(bb + 2*512 + lane*8);
        bf16x8 b3 = *(const bf16x8*)(bb + 3*512 + lane*8);
        bf16x8 b4 = *(const bf16x8*)(bb + 4*512 + lane*8);
        bf16x8 b5 = *(const bf16x8*)(bb + 5*512 + lane*8);
        bf16x8 b6 = *(const bf16x8*)(bb + 6*512 + lane*8);
        bf16x8 b7 = *(const bf16x8*)(bb + 7*512 + lane*8);
        int jp2 = (j+2 > NPAIR-1) ? NPAIR-1 : j+2;
        int n00 = ids_lds[(2*jp2  )*128 + wrow], n01 = ids_lds[(2*jp2  )*128 + wrow + 16];
        int n10 = ids_lds[(2*jp2+1)*128 + wrow], n11 = ids_lds[(2*jp2+1)*128 + wrow + 16];
        int jp1 = (j+1 > NPAIR-1) ? NPAIR-1 : j+1;
        stage(jp1, bsel^1);
        __builtin_amdgcn_sched_barrier(0);
        // MFMA even-k; odd-k B reads interleave in this region
        t0q0 = __builtin_amdgcn_mfma_f32_16x16x32_bf16(AC[0], b0, t0q0, 0,0,0);
        t0q1 = __builtin_amdgcn_mfma_f32_16x16x32_bf16(AC[0], b1, t0q1, 0,0,0);
        t0q2 = __builtin_amdgcn_mfma_f32_16x16x32_bf16(AC[0], b2, t0q2, 0,0,0);
        t0q3 = __builtin_amdgcn_mfma_f32_16x16x32_bf16(AC[0], b3, t0q3, 0,0,0);
        t0q0 = __builtin_amdgcn_mfma_f32_16x16x32_bf16(AC[1], b4, t0q0, 0,0,0);
        t0q1 = __builtin_amdgcn_mfma_f32_16x16x32_bf16(AC[1], b5, t0q1, 0,0,0);
        t0q2 = __builtin_amdgcn_mfma_f32_16x16x32_bf16(AC[1], b6, t0q2, 0,0,0);
        t0q3 = __builtin_amdgcn_mfma_f32_16x16x32_bf16(AC[1], b7, t0q3, 0,0,0);
        t1q0 = __builtin_amdgcn_mfma_f32_16x16x32_bf16(AC[2], b0, t1q0, 0,0,0);
        t1q1 = __builtin_amdgcn_mfma_f32_16x16x32_bf16(AC[2], b1, t1q1, 0,0,0);
        t1q2 = __builtin_amdgcn_mfma_f32_16x16x32_bf16(AC[2], b2, t1q2, 0,0,0);
        t1q3 = __builtin_amdgcn_mfma_f32_16x16x32_bf16(AC[2], b3, t1q3, 0,0,0);
        t1q0 = __builtin_amdgcn_mfma_f32_16x16x32_bf16(AC[3], b4, t1q0, 0,0,0);
        t1q1 = __builtin_amdgcn_mfma_f32_16x16x32_bf16(AC[3], b5, t1q1, 0,0,0);
        t1q2 = __builtin_amdgcn_mfma_f32_16x16x32_bf16(AC[3], b6, t1q2, 0,0,0);
        t1q3 = __builtin_amdgcn_mfma_f32_16x16x32_bf16(AC[3], b7, t1q3, 0,0,0);
        // odd-k B frags (reuse registers)
        b0 = *(const bf16x8*)(bb + 4096 + 0*512 + lane*8);
        b1 = *(const bf16x8*)(bb + 4096 + 1*512 + lane*8);
        b2 = *(const bf16x8*)(bb + 4096 + 2*512 + lane*8);
        b3 = *(const bf16x8*)(bb + 4096 + 3*512 + lane*8);
        b4 = *(const bf16x8*)(bb + 4096 + 4*512 + lane*8);
        b5 = *(const bf16x8*)(bb + 4096 + 5*512 + lane*8);
        b6 = *(const bf16x8*)(bb + 4096 + 6*512 + lane*8);
        b7 = *(const bf16x8*)(bb + 4096 + 7*512 + lane*8);
        t0q0 = __builtin_amdgcn_mfma_f32_16x16x32_bf16(AC[4], b0, t0q0, 0,0,0);
        t0q1 = __builtin_amdgcn_mfma_f32_16x16x32_bf16(AC[4], b1, t0q1, 0,0,0);
        t0q2 = __builtin_amdgcn_mfma_f32_16x16x32_bf16(AC[4], b2, t0q2, 0,0,0);
        t0q3 = __builtin_amdgcn_mfma_f32_16x16x32_bf16(AC[4], b3, t0q3, 0,0,0);
        t0q0 = __builtin_amdgcn_mfma_f32_16x16x32_bf16(AC[5], b4, t0q0, 0,0,0);
        t0q1 = __builtin_amdgcn_mfma_f32_16x16x32_bf16(AC[5], b5, t0q1, 0,0,0);
        t0q2 = __builtin_amdgcn_mfma_f32_16x16x32_bf16(AC[5], b6, t0q2, 0,0,0);
        t0q3 = __builtin_amdgcn_mfma_f32_16x16x32_bf16(AC[5], b7, t0q3, 0,0,0);
        t1q0 = __builtin_amdgcn_mfma_f32_16x16x32_bf16(AC[6], b0, t1q0, 0,0,0);
        t1q1 = __builtin_amdgcn_mfma_f32_16x16x32_bf16(AC[6], b1, t1q1, 0,0,0);
        t1q2 = __builtin_amdgcn_mfma_f32_16x16x32_bf16(AC[6], b2, t1q2, 0,0,0);
        t1q3 = __builtin_amdgcn_mfma_f32_16x16x32_bf16(AC[6], b3, t1q3, 0,0,0);
        t1q0 = __builtin_amdgcn_mfma_f32_16x16x32_bf16(AC[7], b4, t1q0, 0,0,0);
        t1q1 = __builtin_amdgcn_mfma_f32_16x16x32_bf16(AC[7], b5, t1q1, 0,0,0);
        t1q2 = __builtin_amdgcn_mfma_f32_16x16x32_bf16(AC[7], b6, t1q2, 0,0,0);
        t1q3 = __builtin_amdgcn_mfma_f32_16x16x32_bf16(AC[7], b7, t1q3, 0,0,0);
        __builtin_amdgcn_sched_barrier(0);
        LDA8(AC, n00, n01, n10, n11);               // A(pair j+2), after stage: order pinned
        __builtin_amdgcn_sched_barrier(0);
    };

    #pragma unroll 1
    for (int t = 0; t < 7; ++t) {
        phaseP(2*t,   aE);
        phaseP(2*t+1, aO);
    }

    // ---- epilogue: scatter to out[orig pid]; C/D col=lane&15, row=seg*4+j ----
    #pragma unroll
    for (int j = 0; j < 4; ++j) {
        int row0 = p0b + wv*32 + seg*4 + j;
        if (row0 < BN_TOT) {
            int opid = csorted[row0].w;
            float* ob = out + (size_t)opid*64 + r;
            ob[ 0] = t0q0[j]; ob[16] = t0q1[j]; ob[32] = t0q2[j]; ob[48] = t0q3[j];
        }
        int row1 = row0 + 16;
        if (row1 < BN_TOT) {
            int opid = csorted[row1].w;
            float* ob = out + (size_t)opid*64 + r;
            ob[ 0] = t1q0[j]; ob[16] = t1q1[j]; ob[32] = t1q2[j]; ob[48] = t1q3[j];
        }
    }

    // ---- fused stats (pad rows contribute exact zeros) ----
    if (tid < 64) { bsum[tid] = 0.f; bsq[tid] = 0.f; }
    __syncthreads();
    float s0=0,s1=0,s2=0,s3=0,q0=0,q1=0,q2=0,q3=0;
    #pragma unroll
    for (int j = 0; j < 4; ++j) {
        s0 += t0q0[j] + t1q0[j];  q0 += t0q0[j]*t0q0[j] + t1q0[j]*t1q0[j];
        s1 += t0q1[j] + t1q1[j];  q1 += t0q1[j]*t0q1[j] + t1q1[j]*t1q1[j];
        s2 += t0q2[j] + t1q2[j];  q2 += t0q2[j]*t0q2[j] + t1q2[j]*t1q2[j];
        s3 += t0q3[j] + t1q3[j];  q3 += t0q3[j]*t0q3[j] + t1q3[j]*t1q3[j];
    }
    atomicAdd(&bsum[ 0 + r], s0);  atomicAdd(&bsq[ 0 + r], q0);
    atomicAdd(&bsum[16 + r], s1);  atomicAdd(&bsq[16 + r], q1);
    atomicAdd(&bsum[32 + r], s2);  atomicAdd(&bsq[32 + r], q2);
    atomicAdd(&bsum[48 + r], s3);  atomicAdd(&bsq[48 + r], q3);
    __syncthreads();
    if (tid < 64) { atomicAdd(&gstats[tid], bsum[tid]); atomicAdd(&gstats[64+tid], bsq[tid]); }
#undef LDA8
}

// ---------- kernel 7: normalize + affine + ReLU, in place ----------
__global__ __launch_bounds__(256) void k_norm(float* __restrict__ out,
                                              const float* __restrict__ stats,
                                              const float* __restrict__ gamma,
                                              const float* __restrict__ beta) {
    int i = blockIdx.x*256 + threadIdx.x;
    const int n4 = BN_TOT*16;
    if (i >= n4) return;
    float4 v = ((const float4*)out)[i];
    int ch = (i & 15) * 4;
    float o[4] = {v.x, v.y, v.z, v.w};
    float rp[4];
    #pragma unroll
    for (int j = 0; j < 4; ++j) {
        int c = ch + j;
        float mean = stats[c] * (1.f/BN_TOT);
        float var  = stats[64+c] * (1.f/BN_TOT) - mean*mean;
        float y = (o[j] - mean) * rsqrtf(var + EPS) * gamma[c] + beta[c];
        rp[j] = fmaxf(y, 0.f);
    }
    float4 rv; rv.x = rp[0]; rv.y = rp[1]; rv.z = rp[2]; rv.w = rp[3];
    ((float4*)out)[i] = rv;
}

extern "C" void kernel_launch(void* const* d_in, const int* in_sizes, int n_in,
                              void* d_out, int out_size, void* d_ws, size_t ws_size,
                              hipStream_t stream) {
    const float* feats  = (const float*)d_in[0];
    const int*   coords = (const int*)d_in[1];
    const float* weight = (const float*)d_in[2];
    const float* gamma  = (const float*)d_in[3];
    const float* beta   = (const float*)d_in[4];
    float* out = (float*)d_out;

    char*   ws      = (char*)d_ws;
    int*    grid    = (int*)(ws + OFF_GRID);
    short*  wfrag   = (short*)(ws + OFF_WFRAG);
    float*  stats   = (float*)(ws + OFF_STATS);
    u32*    cnt     = (u32*)(ws + OFF_CNT);
    u32*    cur     = (u32*)(ws + OFF_CUR);
    int*    sortidx = (int*)(ws + OFF_SIDX);
    int4*   csorted = (int4*)(ws + OFF_CSORT);
    ushort* fb16s   = (ushort*)(ws + OFF_FB16S);
    int*    idbuf   = (int*)(ws + OFF_IDS);

    hipMemsetAsync(grid,  0xFF, SZ_GRID, stream);
    hipMemsetAsync(stats, 0, 512, stream);
    hipMemsetAsync(cnt,   0, NBKT*4, stream);
    hipMemsetAsync(fb16s + (size_t)BN_TOT*64, 0,
                   (size_t)(BN_PAD + 1 - BN_TOT)*128, stream);   // pads + ZROW

    k_count  <<<(BN_TOT + 255)/256, 256, 0, stream>>>(coords, grid, cnt);
    k_scan   <<<1, 1024, 0, stream>>>(cnt, cur);
    k_place  <<<(BN_PAD + 255)/256, 256, 0, stream>>>(feats, coords, cur,
                                                      sortidx, csorted, fb16s);
    k_ids    <<<(BN_PAD + 255)/256, 256, 0, stream>>>(csorted, grid, sortidx, idbuf);
    k_prefrag<<<(NKS*4096)/256, 256, 0, stream>>>(weight, wfrag);
    k_conv   <<<CONV_BLOCKS, 256, 0, stream>>>(fb16s, csorted, idbuf,
                                               (const ushort*)wfrag, out, stats);
    k_norm   <<<(BN_TOT*16)/256, 256, 0, stream>>>(out, stats, gamma, beta);
}